// Round 6
// baseline (178.409 us; speedup 1.0000x reference)
//
#include <hip/hip_runtime.h>

#define NGRID 512
#define NV (NGRID * NGRID)          // 262144
#define NB 4
#define NVIEWS 4
#define FEPS 1e-6f
#define TR 2                        // owned rows per block
#define LDS_ROWS (TR + 2)           // + top/bottom halo
#define ROWF (NGRID * 3)            // 1536 floats per row
#define LDSF (LDS_ROWS * ROWF)      // 6144 floats = 24 KB

typedef float fvec4 __attribute__((ext_vector_type(4)));

static constexpr size_t NVF3 = (size_t)NV * 3;                      // 786432
static constexpr size_t VERTS_FLOATS = (size_t)NVIEWS * NB * NVF3;  // 12,582,912
static constexpr size_t LAP_OFF = 2 * VERTS_FLOATS;
static constexpr size_t FLAT_OFF = LAP_OFF + 1;

__device__ __forceinline__ float frcp(float x)  { return __builtin_amdgcn_rcpf(x); }
__device__ __forceinline__ float fsqrt_(float x){ return __builtin_amdgcn_sqrtf(x); }

// ---------------------------------------------------------------------------
__global__ void init_losses(float* __restrict__ out) {
    if (threadIdx.x == 0) {
        out[LAP_OFF] = 0.0f;
        out[FLAT_OFF] = 0.0f;
    }
}

// ---------------------------------------------------------------------------
__device__ __forceinline__ float3 ldsP(const float* __restrict__ vs, int lr, int c) {
    const int o = lr * ROWF + c * 3;
    return make_float3(vs[o], vs[o + 1], vs[o + 2]);
}

__device__ __forceinline__ float edge_val(float3 p0, float3 p1, float3 p2, float3 p3) {
    const float a1x = p1.x - p0.x, a1y = p1.y - p0.y, a1z = p1.z - p0.z;
    const float a1l2 = a1x * a1x + a1y * a1y + a1z * a1z;
    const float a1l1 = fsqrt_(a1l2 + FEPS);
    const float inv_a1l2 = frcp(a1l2 + FEPS);

    const float b1x = p2.x - p0.x, b1y = p2.y - p0.y, b1z = p2.z - p0.z;
    const float b1l2 = b1x * b1x + b1y * b1y + b1z * b1z;
    const float b1l1 = fsqrt_(b1l2 + FEPS);
    const float ab1 = a1x * b1x + a1y * b1y + a1z * b1z;
    const float cos1 = ab1 * frcp(a1l1 * b1l1 + FEPS);
    const float sin1 = fsqrt_(1.0f - cos1 * cos1 + FEPS);
    const float f1 = ab1 * inv_a1l2;
    const float cb1x = b1x - a1x * f1, cb1y = b1y - a1y * f1, cb1z = b1z - a1z * f1;
    const float l1 = b1l1 * sin1;

    const float b2x = p3.x - p0.x, b2y = p3.y - p0.y, b2z = p3.z - p0.z;
    const float b2l2 = b2x * b2x + b2y * b2y + b2z * b2z;
    const float b2l1 = fsqrt_(b2l2 + FEPS);
    const float ab2 = a1x * b2x + a1y * b2y + a1z * b2z;
    const float cos2 = ab2 * frcp(a1l1 * b2l1 + FEPS);
    const float sin2 = fsqrt_(1.0f - cos2 * cos2 + FEPS);
    const float f2 = ab2 * inv_a1l2;
    const float cb2x = b2x - a1x * f2, cb2y = b2y - a1y * f2, cb2z = b2z - a1z * f2;
    const float l2 = b2l1 * sin2;

    const float cosd = (cb1x * cb2x + cb1y * cb2y + cb1z * cb2z) * frcp(l1 * l2 + FEPS);
    const float t = cosd + 1.0f;
    return t * t;
}

// ---------------------------------------------------------------------------
// Mega-kernel: one block = (2-row tile, batch). Stages v (with 1-row halo)
// in LDS via recompute. After the barrier, waves 0-1 and waves 2-3 execute
// the (stores, loss) phases in OPPOSITE order on disjoint halves, so the
// CU's memory pipe (store drain) and VALU pipe (loss compute) are both fed
// at all times instead of serializing in lockstep.
__global__ __launch_bounds__(256) void mesh_fused_kernel(
    const float* __restrict__ disp, const float* __restrict__ center,
    const float* __restrict__ tex, const float* __restrict__ tv,
    float* __restrict__ out)
{
    __shared__ float vs[LDSF];
    const int tid = threadIdx.x;
    const int b = blockIdx.y;
    const int R0 = blockIdx.x * TR;

    const float c0 = tanhf(center[b * 3 + 0]);
    const float c1 = tanhf(center[b * 3 + 1]);
    const float c2 = tanhf(center[b * 3 + 2]);
    const float carr[3] = {c0, c1, c2};

    // ---- Stage v for rows [R0-1, R0+TR] into LDS (float4 vectorized) ----
    {
        const fvec4* __restrict__ tv4 = (const fvec4*)tv;
        const fvec4* __restrict__ d4p = (const fvec4*)(disp + (size_t)b * NVF3);
        fvec4* __restrict__ vs4 = (fvec4*)vs;
        const int start4 = (R0 - 1) * (ROWF / 4);          // may be negative (tile 0)
#pragma unroll
        for (int ss = 0; ss < LDSF / 4 / 256; ++ss) {
            const int ff4 = ss * 256 + tid;
            const int g4 = start4 + ff4;
            if (g4 < 0 || g4 >= (int)(NVF3 / 4)) continue;
            const fvec4 t = tv4[g4];
            const fvec4 d = d4p[g4];
            fvec4 vr;
            int comp = ff4 % 3;   // (4*g4)%3 == g4%3 == ff4%3 (start4 % 3 == 0)
#pragma unroll
            for (int l = 0; l < 4; ++l) {
                const float tvl = t[l];
                const float s = fabsf(tvl);
                const float sgn = (tvl > 0.0f) ? 1.0f : -1.0f;
                // sigma = sigmoid(log(s/(1-s)) + d) = s / (s + (1-s)*exp(-d))
                const float e = __expf(-d[l]);
                const float sigma = s * frcp(fmaf(1.0f - s, e, s));
                // v = relu(v0)(1-c) - relu(-v0)(1+c) + c  ==  sigma*(sgn - c) + c
                const float c = carr[comp];
                vr[l] = fmaf(sigma, sgn - c, c);
                comp = (comp == 2) ? 0 : comp + 1;
            }
            vs4[ff4] = vr;
        }
    }
    __syncthreads();

    const int half = tid >> 7;       // 0: waves 0-1, 1: waves 2-3
    const int htid = tid & 127;
    float lap_sum = 0.0f, flat_sum = 0.0f;

    // ---- Phase bodies (disjoint halves, 128-thread slices) ----
    // Stores: TR*ROWF/4 = 768 float4 chunks total; group g owns [g*384, g*384+384).
    auto do_stores = [&](int g) {
        const fvec4* __restrict__ vs4 = (const fvec4*)vs;
        const fvec4* __restrict__ t4p = (const fvec4*)(tex + (size_t)b * NVF3);
        fvec4* __restrict__ out4 = (fvec4*)out;
        const size_t blk4 = NVF3 / 4;                       // 196608
        const int tile_base4 = R0 * (ROWF / 4);             // float4 offset of row R0
#pragma unroll
        for (int qq = 0; qq < 3; ++qq) {                    // 3 * 128 = 384 chunks
            const int q = g * 384 + qq * 128 + htid;
            const fvec4 vo = vs4[ROWF / 4 + q];             // skip halo row
            const fvec4 tx = t4p[tile_base4 + q];
            const size_t pos4 = (size_t)tile_base4 + q;
#pragma unroll
            for (int view = 0; view < NVIEWS; ++view) {
                const size_t base = (size_t)(b * NVIEWS + view) * blk4;
                out4[base + pos4] = vo;
                out4[(VERTS_FLOATS / 4) + base + pos4] = tx;
            }
        }
    };

    // Loss: TR*NGRID = 1024 vertices; group g owns tile row r_off = g (512 verts).
    auto do_loss = [&](int g) {
#pragma unroll 1
        for (int it = 0; it < 4; ++it) {                    // 4 * 128 = 512 verts
            const int c = it * 128 + htid;                  // 0..511
            const int gr = R0 + g;                          // global row
            const int lr = g + 1;                           // LDS row

            const float3 pc = ldsP(vs, lr, c);

            // Laplacian
            {
                float sx = 0.f, sy = 0.f, sz = 0.f;
                int deg = 0;
                if (gr > 0)               { float3 p = ldsP(vs, lr - 1, c);     sx += p.x; sy += p.y; sz += p.z; deg++; }
                if (gr < NGRID - 1)       { float3 p = ldsP(vs, lr + 1, c);     sx += p.x; sy += p.y; sz += p.z; deg++; }
                if (c > 0)                { float3 p = ldsP(vs, lr, c - 1);     sx += p.x; sy += p.y; sz += p.z; deg++; }
                if (c < NGRID - 1)        { float3 p = ldsP(vs, lr, c + 1);     sx += p.x; sy += p.y; sz += p.z; deg++; }
                if (gr > 0 && c < NGRID - 1)      { float3 p = ldsP(vs, lr - 1, c + 1); sx += p.x; sy += p.y; sz += p.z; deg++; }
                if (gr < NGRID - 1 && c > 0)      { float3 p = ldsP(vs, lr + 1, c - 1); sx += p.x; sy += p.y; sz += p.z; deg++; }
                const float id = frcp((float)deg);
                const float lx = pc.x - sx * id;
                const float ly = pc.y - sy * id;
                const float lz = pc.z - sz * id;
                lap_sum += lx * lx + ly * ly + lz * lz;
            }

            // Flat loss: up to 3 structural edges anchored at (gr, c)
            if (gr < NGRID - 1 && c < NGRID - 1) {
                flat_sum += edge_val(ldsP(vs, lr, c + 1), ldsP(vs, lr + 1, c),
                                     pc,                  ldsP(vs, lr + 1, c + 1));
            }
            if (gr >= 1 && gr < NGRID - 1 && c < NGRID - 1) {
                flat_sum += edge_val(pc, ldsP(vs, lr, c + 1),
                                     ldsP(vs, lr + 1, c), ldsP(vs, lr - 1, c + 1));
            }
            if (gr < NGRID - 1 && c >= 1 && c < NGRID - 1) {
                flat_sum += edge_val(pc, ldsP(vs, lr + 1, c),
                                     ldsP(vs, lr, c + 1), ldsP(vs, lr + 1, c - 1));
            }
        }
    };

    // ---- Opposite phase order per wave group: overlap store drain w/ VALU ----
    if (half == 0) {
        do_stores(0);
        do_loss(0);
    } else {
        do_loss(1);
        do_stores(1);
    }

    // ---- Block reduction (two values), one atomic pair per block ----
#pragma unroll
    for (int off = 32; off > 0; off >>= 1) {
        lap_sum  += __shfl_down(lap_sum, off, 64);
        flat_sum += __shfl_down(flat_sum, off, 64);
    }
    __shared__ float red[8];
    const int lane = tid & 63;
    const int wid = tid >> 6;
    if (lane == 0) { red[wid] = lap_sum; red[4 + wid] = flat_sum; }
    __syncthreads();
    if (tid == 0) {
        const float ls = red[0] + red[1] + red[2] + red[3];
        const float fs = red[4] + red[5] + red[6] + red[7];
        atomicAdd(&out[LAP_OFF],  ls * (1.0f / NB));
        atomicAdd(&out[FLAT_OFF], fs * (1.0f / NB));
    }
}

// ---------------------------------------------------------------------------
extern "C" void kernel_launch(void* const* d_in, const int* in_sizes, int n_in,
                              void* d_out, int out_size, void* d_ws, size_t ws_size,
                              hipStream_t stream)
{
    const float* disp   = (const float*)d_in[0];
    const float* center = (const float*)d_in[1];
    const float* tex    = (const float*)d_in[2];
    const float* tv     = (const float*)d_in[3];
    float* out = (float*)d_out;

    init_losses<<<1, 64, 0, stream>>>(out);
    mesh_fused_kernel<<<dim3(NGRID / TR, NB), 256, 0, stream>>>(disp, center, tex, tv, out);
}

// Round 7
// 176.064 us; speedup vs baseline: 1.0133x; 1.0133x over previous
//
#include <hip/hip_runtime.h>

#define NGRID 512
#define NV (NGRID * NGRID)          // 262144
#define NB 4
#define NVIEWS 4
#define FEPS 1e-6f
#define TR 2                        // owned rows per block
#define LDS_ROWS (TR + 2)           // + top/bottom halo
#define ROWF (NGRID * 3)            // 1536 packed floats per row
#define LDSF4 (LDS_ROWS * ROWF / 4) // 1536 staged float4 chunks per tile
#define SROW 640                    // skewed slots per row: 512 + 512/4

typedef float fvec4 __attribute__((ext_vector_type(4)));

static constexpr size_t NVF3 = (size_t)NV * 3;                      // 786432
static constexpr size_t VERTS_FLOATS = (size_t)NVIEWS * NB * NVF3;  // 12,582,912
static constexpr size_t LAP_OFF = 2 * VERTS_FLOATS;
static constexpr size_t FLAT_OFF = LAP_OFF + 1;

__device__ __forceinline__ float frcp(float x)  { return __builtin_amdgcn_rcpf(x); }
__device__ __forceinline__ float fsqrt_(float x){ return __builtin_amdgcn_sqrtf(x); }

// ---------------------------------------------------------------------------
__global__ void init_losses(float* __restrict__ out) {
    if (threadIdx.x == 0) {
        out[LAP_OFF] = 0.0f;
        out[FLAT_OFF] = 0.0f;
    }
}

// ---------------------------------------------------------------------------
__device__ __forceinline__ float edge_val(fvec4 p0, fvec4 p1, fvec4 p2, fvec4 p3) {
    const float a1x = p1.x - p0.x, a1y = p1.y - p0.y, a1z = p1.z - p0.z;
    const float a1l2 = a1x * a1x + a1y * a1y + a1z * a1z;
    const float a1l1 = fsqrt_(a1l2 + FEPS);
    const float inv_a1l2 = frcp(a1l2 + FEPS);

    const float b1x = p2.x - p0.x, b1y = p2.y - p0.y, b1z = p2.z - p0.z;
    const float b1l2 = b1x * b1x + b1y * b1y + b1z * b1z;
    const float b1l1 = fsqrt_(b1l2 + FEPS);
    const float ab1 = a1x * b1x + a1y * b1y + a1z * b1z;
    const float cos1 = ab1 * frcp(a1l1 * b1l1 + FEPS);
    const float sin1 = fsqrt_(1.0f - cos1 * cos1 + FEPS);
    const float f1 = ab1 * inv_a1l2;
    const float cb1x = b1x - a1x * f1, cb1y = b1y - a1y * f1, cb1z = b1z - a1z * f1;
    const float l1 = b1l1 * sin1;

    const float b2x = p3.x - p0.x, b2y = p3.y - p0.y, b2z = p3.z - p0.z;
    const float b2l2 = b2x * b2x + b2y * b2y + b2z * b2z;
    const float b2l1 = fsqrt_(b2l2 + FEPS);
    const float ab2 = a1x * b2x + a1y * b2y + a1z * b2z;
    const float cos2 = ab2 * frcp(a1l1 * b2l1 + FEPS);
    const float sin2 = fsqrt_(1.0f - cos2 * cos2 + FEPS);
    const float f2 = ab2 * inv_a1l2;
    const float cb2x = b2x - a1x * f2, cb2y = b2y - a1y * f2, cb2z = b2z - a1z * f2;
    const float l2 = b2l1 * sin2;

    const float cosd = (cb1x * cb2x + cb1y * cb2y + cb1z * cb2z) * frcp(l1 * l2 + FEPS);
    const float t = cosd + 1.0f;
    return t * t;
}

// ---------------------------------------------------------------------------
// Mega-kernel: one block = (2-row tile, batch). Stages v (with 1-row halo)
// into SKEWED float4-per-point LDS (slot = r*640 + c + (c>>2)); the skew
// makes wave-wide strip reads (lane stride 4 cols = 80 B) cover all 32
// banks every 8 lanes -> conflict-free-optimal ds_read_b128.
// Loss phase: each thread owns a 1x4 column strip, loads its 3x6-point
// neighborhood with 18 ds_read_b128 and computes 4 vertices from registers
// (vs 228 scalar ds_read_b32 before). Store phase & all math unchanged.
__global__ __launch_bounds__(256) void mesh_fused_kernel(
    const float* __restrict__ disp, const float* __restrict__ center,
    const float* __restrict__ tex, const float* __restrict__ tv,
    float* __restrict__ out)
{
    __shared__ fvec4 vsp[LDS_ROWS * SROW];          // 40 KB
    float* __restrict__ vs_f = (float*)vsp;

    const int tid = threadIdx.x;
    const int b = blockIdx.y;
    const int R0 = blockIdx.x * TR;

    const float c0c = tanhf(center[b * 3 + 0]);
    const float c1c = tanhf(center[b * 3 + 1]);
    const float c2c = tanhf(center[b * 3 + 2]);
    const float carr[3] = {c0c, c1c, c2c};

    // ---- Stage v for rows [R0-1, R0+TR] into skewed LDS ----
    {
        const fvec4* __restrict__ tv4 = (const fvec4*)tv;
        const fvec4* __restrict__ d4p = (const fvec4*)(disp + (size_t)b * NVF3);
        const int start4 = (R0 - 1) * (ROWF / 4);          // may be negative (tile 0)
#pragma unroll
        for (int ss = 0; ss < LDSF4 / 256; ++ss) {         // 6 iters
            const int ff4 = ss * 256 + tid;
            const int g4 = start4 + ff4;
            if (g4 < 0 || g4 >= (int)(NVF3 / 4)) continue;
            const fvec4 t = tv4[g4];
            const fvec4 d = d4p[g4];
            fvec4 vr;
            {
                int comp = ff4 % 3;   // (4*g4)%3 == g4%3 == ff4%3 (start4 % 3 == 0)
#pragma unroll
                for (int l = 0; l < 4; ++l) {
                    const float tvl = t[l];
                    const float s = fabsf(tvl);
                    const float sgn = (tvl > 0.0f) ? 1.0f : -1.0f;
                    // sigma = sigmoid(log(s/(1-s)) + d) = s / (s + (1-s)*exp(-d))
                    const float e = __expf(-d[l]);
                    const float sigma = s * frcp(fmaf(1.0f - s, e, s));
                    // v = relu(v0)(1-c) - relu(-v0)(1+c) + c == sigma*(sgn-c)+c
                    const float c = carr[comp];
                    vr[l] = fmaf(sigma, sgn - c, c);
                    comp = (comp == 2) ? 0 : comp + 1;
                }
            }
            // Scatter into skewed float4-per-point layout.
            // ff4 = 3k+m -> first point 4k+m, first comp m (verified pattern).
            {
                const int k = ff4 / 3;
                const int m = ff4 - 3 * k;
                int point = 4 * k + m;
                int comp = m;
#pragma unroll
                for (int l = 0; l < 4; ++l) {
                    const int row = point >> 9;
                    const int col = point & (NGRID - 1);
                    const int slot = row * SROW + col + (col >> 2);
                    vs_f[slot * 4 + comp] = vr[l];
                    comp++;
                    if (comp == 3) { comp = 0; point++; }
                }
            }
        }
    }
    __syncthreads();

    // ---- Write verts x4 views + tex x4 views for owned rows ----
    {
        const fvec4* __restrict__ t4p = (const fvec4*)(tex + (size_t)b * NVF3);
        fvec4* __restrict__ out4 = (fvec4*)out;
        const size_t blk4 = NVF3 / 4;                       // 196608
        const int tile_base4 = R0 * (ROWF / 4);             // float4 offset of row R0
#pragma unroll
        for (int qq = 0; qq < TR * ROWF / 4 / 256; ++qq) {  // 3 iters
            const int q = qq * 256 + tid;
            // Gather the packed chunk (floats 4*(384+q)..+3) from skewed LDS.
            fvec4 vo;
            {
                const int qt = (ROWF / 4) + q;              // skip halo row
                const int k = qt / 3;
                const int m = qt - 3 * k;
                int point = 4 * k + m;
                int comp = m;
#pragma unroll
                for (int l = 0; l < 4; ++l) {
                    const int row = point >> 9;
                    const int col = point & (NGRID - 1);
                    const int slot = row * SROW + col + (col >> 2);
                    vo[l] = vs_f[slot * 4 + comp];
                    comp++;
                    if (comp == 3) { comp = 0; point++; }
                }
            }
            const fvec4 tx = t4p[tile_base4 + q];
            const size_t pos4 = (size_t)tile_base4 + q;
#pragma unroll
            for (int view = 0; view < NVIEWS; ++view) {
                const size_t base = (size_t)(b * NVIEWS + view) * blk4;
                out4[base + pos4] = vo;
                out4[(VERTS_FLOATS / 4) + base + pos4] = tx;
            }
        }
    }

    // ---- Lap + flat losses: 1x4 column strip per thread, register 3x6 cache ----
    float lap_sum = 0.0f, flat_sum = 0.0f;
    {
        const int rofs = tid >> 7;             // 0..1 (owned tile row)
        const int strip = tid & 127;
        const int cb = strip * 4;              // first owned column
        const int gr = R0 + rofs;              // global row (wave-uniform guard)
        const int lr = rofs + 1;               // LDS row of owned row

        const int cm1 = (cb > 0) ? cb - 1 : 0;             // clamped (unused when clamped)
        const int cp4 = (cb + 4 < NGRID) ? cb + 4 : NGRID - 1;
        const int cols[6] = {cm1, cb, cb + 1, cb + 2, cb + 3, cp4};

        fvec4 P[3][6];
#pragma unroll
        for (int r = 0; r < 3; ++r) {
            const int rbase = (lr - 1 + r) * SROW;
#pragma unroll
            for (int kk = 0; kk < 6; ++kk) {
                const int cc = cols[kk];
                P[r][kk] = vsp[rbase + cc + (cc >> 2)];
            }
        }

#pragma unroll
        for (int j = 0; j < 4; ++j) {
            const int c = cb + j;
            const fvec4 C  = P[1][j + 1];
            const fvec4 Nn = P[0][j + 1];
            const fvec4 S  = P[2][j + 1];
            const fvec4 W  = P[1][j];
            const fvec4 E  = P[1][j + 2];
            const fvec4 NE = P[0][j + 2];
            const fvec4 SW = P[2][j];
            const fvec4 SE = P[2][j + 2];

            // Laplacian (6-neighborhood of the unique-edge graph)
            {
                float sx = 0.f, sy = 0.f, sz = 0.f;
                int deg = 0;
                if (gr > 0)               { sx += Nn.x; sy += Nn.y; sz += Nn.z; deg++; }
                if (gr < NGRID - 1)       { sx += S.x;  sy += S.y;  sz += S.z;  deg++; }
                if (c > 0)                { sx += W.x;  sy += W.y;  sz += W.z;  deg++; }
                if (c < NGRID - 1)        { sx += E.x;  sy += E.y;  sz += E.z;  deg++; }
                if (gr > 0 && c < NGRID - 1)      { sx += NE.x; sy += NE.y; sz += NE.z; deg++; }
                if (gr < NGRID - 1 && c > 0)      { sx += SW.x; sy += SW.y; sz += SW.z; deg++; }
                const float id = frcp((float)deg);
                const float lx = C.x - sx * id;
                const float ly = C.y - sy * id;
                const float lz = C.z - sz * id;
                lap_sum += lx * lx + ly * ly + lz * lz;
            }

            // Flat loss: up to 3 structural edges anchored at (gr, c)
            if (gr < NGRID - 1 && c < NGRID - 1) {
                flat_sum += edge_val(E, S, C, SE);
            }
            if (gr >= 1 && gr < NGRID - 1 && c < NGRID - 1) {
                flat_sum += edge_val(C, E, S, NE);
            }
            if (gr < NGRID - 1 && c >= 1 && c < NGRID - 1) {
                flat_sum += edge_val(C, S, E, SW);
            }
        }
    }

    // ---- Block reduction (two values), one atomic pair per block ----
#pragma unroll
    for (int off = 32; off > 0; off >>= 1) {
        lap_sum  += __shfl_down(lap_sum, off, 64);
        flat_sum += __shfl_down(flat_sum, off, 64);
    }
    __shared__ float red[8];
    const int lane = tid & 63;
    const int wid = tid >> 6;
    if (lane == 0) { red[wid] = lap_sum; red[4 + wid] = flat_sum; }
    __syncthreads();
    if (tid == 0) {
        const float ls = red[0] + red[1] + red[2] + red[3];
        const float fs = red[4] + red[5] + red[6] + red[7];
        atomicAdd(&out[LAP_OFF],  ls * (1.0f / NB));
        atomicAdd(&out[FLAT_OFF], fs * (1.0f / NB));
    }
}

// ---------------------------------------------------------------------------
extern "C" void kernel_launch(void* const* d_in, const int* in_sizes, int n_in,
                              void* d_out, int out_size, void* d_ws, size_t ws_size,
                              hipStream_t stream)
{
    const float* disp   = (const float*)d_in[0];
    const float* center = (const float*)d_in[1];
    const float* tex    = (const float*)d_in[2];
    const float* tv     = (const float*)d_in[3];
    float* out = (float*)d_out;

    init_losses<<<1, 64, 0, stream>>>(out);
    mesh_fused_kernel<<<dim3(NGRID / TR, NB), 256, 0, stream>>>(disp, center, tex, tv, out);
}

// Round 8
// 173.352 us; speedup vs baseline: 1.0292x; 1.0156x over previous
//
#include <hip/hip_runtime.h>

#define NGRID 512
#define NV (NGRID * NGRID)          // 262144
#define NB 4
#define NVIEWS 4
#define FEPS 1e-6f
#define TR 2                        // owned rows per block
#define LDS_ROWS (TR + 2)           // + top/bottom halo
#define ROWF (NGRID * 3)            // 1536 floats per row
#define ROW4 (ROWF / 4)             // 384 float4 chunks per row
#define LDSF (LDS_ROWS * ROWF)      // 6144 floats = 24 KB

typedef float fvec4 __attribute__((ext_vector_type(4)));

static constexpr size_t NVF3 = (size_t)NV * 3;                      // 786432
static constexpr size_t VERTS_FLOATS = (size_t)NVIEWS * NB * NVF3;  // 12,582,912
static constexpr size_t LAP_OFF = 2 * VERTS_FLOATS;
static constexpr size_t FLAT_OFF = LAP_OFF + 1;

__device__ __forceinline__ float frcp(float x)  { return __builtin_amdgcn_rcpf(x); }
__device__ __forceinline__ float fsqrt_(float x){ return __builtin_amdgcn_sqrtf(x); }

// ---------------------------------------------------------------------------
__global__ void init_losses(float* __restrict__ out) {
    if (threadIdx.x == 0) {
        out[LAP_OFF] = 0.0f;
        out[FLAT_OFF] = 0.0f;
    }
}

// ---------------------------------------------------------------------------
__device__ __forceinline__ float edge_val(float3 p0, float3 p1, float3 p2, float3 p3) {
    const float a1x = p1.x - p0.x, a1y = p1.y - p0.y, a1z = p1.z - p0.z;
    const float a1l2 = a1x * a1x + a1y * a1y + a1z * a1z;
    const float a1l1 = fsqrt_(a1l2 + FEPS);
    const float inv_a1l2 = frcp(a1l2 + FEPS);

    const float b1x = p2.x - p0.x, b1y = p2.y - p0.y, b1z = p2.z - p0.z;
    const float b1l2 = b1x * b1x + b1y * b1y + b1z * b1z;
    const float b1l1 = fsqrt_(b1l2 + FEPS);
    const float ab1 = a1x * b1x + a1y * b1y + a1z * b1z;
    const float cos1 = ab1 * frcp(a1l1 * b1l1 + FEPS);
    const float sin1 = fsqrt_(1.0f - cos1 * cos1 + FEPS);
    const float f1 = ab1 * inv_a1l2;
    const float cb1x = b1x - a1x * f1, cb1y = b1y - a1y * f1, cb1z = b1z - a1z * f1;
    const float l1 = b1l1 * sin1;

    const float b2x = p3.x - p0.x, b2y = p3.y - p0.y, b2z = p3.z - p0.z;
    const float b2l2 = b2x * b2x + b2y * b2y + b2z * b2z;
    const float b2l1 = fsqrt_(b2l2 + FEPS);
    const float ab2 = a1x * b2x + a1y * b2y + a1z * b2z;
    const float cos2 = ab2 * frcp(a1l1 * b2l1 + FEPS);
    const float sin2 = fsqrt_(1.0f - cos2 * cos2 + FEPS);
    const float f2 = ab2 * inv_a1l2;
    const float cb2x = b2x - a1x * f2, cb2y = b2y - a1y * f2, cb2z = b2z - a1z * f2;
    const float l2 = b2l1 * sin2;

    const float cosd = (cb1x * cb2x + cb1y * cb2y + cb1z * cb2z) * frcp(l1 * l2 + FEPS);
    const float t = cosd + 1.0f;
    return t * t;
}

// ---------------------------------------------------------------------------
// Mega-kernel: one block = (2-row tile, batch).
//  - Staging + store phases: R1-verified code (packed float3 LDS, 24 KB,
//    vectorized fvec4 writes/reads) — unchanged.
//  - Loss phase: each thread owns a 1x4 column strip [4t, 4t+4). Its 6-col
//    neighborhood cols [4t-1, 4t+5) = floats [12t-3, 12t+18) sits inside
//    chunks [3t-1, 3t+5): 6 aligned ds_read_b128 per row x 3 rows = 18
//    b128 loads replacing 228 scalar ds_read_b32 per 4 vertices. Window
//    offset within the 24-float read is the compile-time constant 1.
__global__ __launch_bounds__(256) void mesh_fused_kernel(
    const float* __restrict__ disp, const float* __restrict__ center,
    const float* __restrict__ tex, const float* __restrict__ tv,
    float* __restrict__ out)
{
    // +4 chunks pad: strip reads at t=127 touch chunk 385 of the last row.
    __shared__ fvec4 vs4s[LDS_ROWS * ROW4 + 4];
    float* __restrict__ vs = (float*)vs4s;

    const int tid = threadIdx.x;
    const int b = blockIdx.y;
    const int R0 = blockIdx.x * TR;

    const float c0 = tanhf(center[b * 3 + 0]);
    const float c1 = tanhf(center[b * 3 + 1]);
    const float c2 = tanhf(center[b * 3 + 2]);
    const float carr[3] = {c0, c1, c2};

    // ---- Stage v for rows [R0-1, R0+TR] into LDS (float4 vectorized) ----
    {
        const fvec4* __restrict__ tv4 = (const fvec4*)tv;
        const fvec4* __restrict__ d4p = (const fvec4*)(disp + (size_t)b * NVF3);
        const int start4 = (R0 - 1) * ROW4;                // may be negative (tile 0)
#pragma unroll
        for (int ss = 0; ss < LDSF / 4 / 256; ++ss) {
            const int ff4 = ss * 256 + tid;
            const int g4 = start4 + ff4;
            if (g4 < 0 || g4 >= (int)(NVF3 / 4)) continue;
            const fvec4 t = tv4[g4];
            const fvec4 d = d4p[g4];
            fvec4 vr;
            int comp = ff4 % 3;   // (4*g4)%3 == g4%3 == ff4%3 (start4 % 3 == 0)
#pragma unroll
            for (int l = 0; l < 4; ++l) {
                const float tvl = t[l];
                const float s = fabsf(tvl);
                const float sgn = (tvl > 0.0f) ? 1.0f : -1.0f;
                // sigma = sigmoid(log(s/(1-s)) + d) = s / (s + (1-s)*exp(-d))
                const float e = __expf(-d[l]);
                const float sigma = s * frcp(fmaf(1.0f - s, e, s));
                // v = relu(v0)(1-c) - relu(-v0)(1+c) + c  ==  sigma*(sgn - c) + c
                const float c = carr[comp];
                vr[l] = fmaf(sigma, sgn - c, c);
                comp = (comp == 2) ? 0 : comp + 1;
            }
            vs4s[ff4] = vr;
        }
    }
    __syncthreads();

    // ---- Write verts x4 views + tex x4 views for owned rows ----
    {
        const fvec4* __restrict__ t4p = (const fvec4*)(tex + (size_t)b * NVF3);
        fvec4* __restrict__ out4 = (fvec4*)out;
        const size_t blk4 = NVF3 / 4;                       // 196608
        const int tile_base4 = R0 * ROW4;                   // float4 offset of row R0
#pragma unroll
        for (int qq = 0; qq < TR * ROW4 / 256; ++qq) {
            const int q = qq * 256 + tid;
            const fvec4 vo = vs4s[ROW4 + q];                // skip halo row
            const fvec4 tx = t4p[tile_base4 + q];
            const size_t pos4 = (size_t)tile_base4 + q;
#pragma unroll
            for (int view = 0; view < NVIEWS; ++view) {
                const size_t base = (size_t)(b * NVIEWS + view) * blk4;
                out4[base + pos4] = vo;
                out4[(VERTS_FLOATS / 4) + base + pos4] = tx;
            }
        }
    }

    // ---- Lap + flat losses: 1x4 strip per thread, 18 ds_read_b128 ----
    float lap_sum = 0.0f, flat_sum = 0.0f;
    {
        const int rofs = tid >> 7;             // owned tile row 0..1
        const int t = tid & 127;               // strip index
        const int cb = t * 4;                  // first owned column
        const int gr = R0 + rofs;              // global row (guards)
        const int lr = rofs + 1;               // LDS row of owned row

        // Load the 3x6-chunk window. Chunk j0+k, j0 = 3t-1 (clamped at t=0;
        // the clamped chunk only feeds point p=0 = col -1, which is guarded).
        fvec4 wch[3][6];
        const int j0 = 3 * t - 1;
#pragma unroll
        for (int r = 0; r < 3; ++r) {
            const int rowbase4 = (lr - 1 + r) * ROW4;
#pragma unroll
            for (int k = 0; k < 6; ++k) {
                int jc = j0 + k;
                if (jc < 0) jc = 0;
                wch[r][k] = vs4s[rowbase4 + jc];
            }
        }

        // Component i of point p (col cb-1+p) in window row r:
        // float index 3p+1+i within the 24-float window.
#define GETC(r, p, i) (wch[r][(3 * (p) + 1 + (i)) >> 2][(3 * (p) + 1 + (i)) & 3])
#define GETP(r, p) make_float3(GETC(r, p, 0), GETC(r, p, 1), GETC(r, p, 2))

#pragma unroll
        for (int j = 0; j < 4; ++j) {
            const int c = cb + j;
            const float3 C  = GETP(1, j + 1);
            const float3 Nn = GETP(0, j + 1);
            const float3 S  = GETP(2, j + 1);
            const float3 W  = GETP(1, j);
            const float3 E  = GETP(1, j + 2);
            const float3 NE = GETP(0, j + 2);
            const float3 SW = GETP(2, j);
            const float3 SE = GETP(2, j + 2);

            // Laplacian (6-neighborhood of the unique-edge graph)
            {
                float sx = 0.f, sy = 0.f, sz = 0.f;
                int deg = 0;
                if (gr > 0)               { sx += Nn.x; sy += Nn.y; sz += Nn.z; deg++; }
                if (gr < NGRID - 1)       { sx += S.x;  sy += S.y;  sz += S.z;  deg++; }
                if (c > 0)                { sx += W.x;  sy += W.y;  sz += W.z;  deg++; }
                if (c < NGRID - 1)        { sx += E.x;  sy += E.y;  sz += E.z;  deg++; }
                if (gr > 0 && c < NGRID - 1)      { sx += NE.x; sy += NE.y; sz += NE.z; deg++; }
                if (gr < NGRID - 1 && c > 0)      { sx += SW.x; sy += SW.y; sz += SW.z; deg++; }
                const float id = frcp((float)deg);
                const float lx = C.x - sx * id;
                const float ly = C.y - sy * id;
                const float lz = C.z - sz * id;
                lap_sum += lx * lx + ly * ly + lz * lz;
            }

            // Flat loss: up to 3 structural edges anchored at (gr, c)
            if (gr < NGRID - 1 && c < NGRID - 1) {
                flat_sum += edge_val(E, S, C, SE);
            }
            if (gr >= 1 && gr < NGRID - 1 && c < NGRID - 1) {
                flat_sum += edge_val(C, E, S, NE);
            }
            if (gr < NGRID - 1 && c >= 1 && c < NGRID - 1) {
                flat_sum += edge_val(C, S, E, SW);
            }
        }
#undef GETC
#undef GETP
    }

    // ---- Block reduction (two values), one atomic pair per block ----
#pragma unroll
    for (int off = 32; off > 0; off >>= 1) {
        lap_sum  += __shfl_down(lap_sum, off, 64);
        flat_sum += __shfl_down(flat_sum, off, 64);
    }
    __shared__ float red[8];
    const int lane = tid & 63;
    const int wid = tid >> 6;
    if (lane == 0) { red[wid] = lap_sum; red[4 + wid] = flat_sum; }
    __syncthreads();
    if (tid == 0) {
        const float ls = red[0] + red[1] + red[2] + red[3];
        const float fs = red[4] + red[5] + red[6] + red[7];
        atomicAdd(&out[LAP_OFF],  ls * (1.0f / NB));
        atomicAdd(&out[FLAT_OFF], fs * (1.0f / NB));
    }
}

// ---------------------------------------------------------------------------
extern "C" void kernel_launch(void* const* d_in, const int* in_sizes, int n_in,
                              void* d_out, int out_size, void* d_ws, size_t ws_size,
                              hipStream_t stream)
{
    const float* disp   = (const float*)d_in[0];
    const float* center = (const float*)d_in[1];
    const float* tex    = (const float*)d_in[2];
    const float* tv     = (const float*)d_in[3];
    float* out = (float*)d_out;

    init_losses<<<1, 64, 0, stream>>>(out);
    mesh_fused_kernel<<<dim3(NGRID / TR, NB), 256, 0, stream>>>(disp, center, tex, tv, out);
}